// Round 9
// baseline (901.325 us; speedup 1.0000x reference)
//
#include <hip/hip_runtime.h>

#define NB_ 16
#define TQ_ 2048
#define TS_ 2048
#define DH_ 1024
#define QB_ 32
#define SB_ 128
#define NT_ 512

typedef _Float16 f16x8 __attribute__((ext_vector_type(8)));
typedef _Float16 f16x4 __attribute__((ext_vector_type(4)));
typedef float f32x4 __attribute__((ext_vector_type(4)));

// Barrier that does NOT drain vmcnt: LDS-domain sync only. In-flight global
// loads (V prefetch) survive; compiler inserts its own vmcnt before their use.
#define LDS_BARRIER() asm volatile("s_waitcnt lgkmcnt(0)\n\ts_barrier" ::: "memory")

__device__ inline uint32_t pack_h2(float a, float b) {
  union { _Float16 h[2]; uint32_t u; } c;
  c.h[0] = (_Float16)a; c.h[1] = (_Float16)b;
  return c.u;
}

__global__ void convert_f32_f16(const float* __restrict__ src, _Float16* __restrict__ dst) {
  size_t i = ((size_t)blockIdx.x * blockDim.x + threadIdx.x) * 8;
  float4 v0 = *(const float4*)(src + i);
  float4 v1 = *(const float4*)(src + i + 4);
  f16x8 o;
  o[0] = (_Float16)v0.x; o[1] = (_Float16)v0.y; o[2] = (_Float16)v0.z; o[3] = (_Float16)v0.w;
  o[4] = (_Float16)v1.x; o[5] = (_Float16)v1.y; o[6] = (_Float16)v1.z; o[7] = (_Float16)v1.w;
  *(f16x8*)(dst + i) = o;
}

template<bool WS16>
__device__ inline f16x8 ld8(const _Float16* __restrict__ hp, const float* __restrict__ fp, size_t idx) {
  if constexpr (WS16) {
    return *(const f16x8*)(hp + idx);
  } else {
    float4 a = *(const float4*)(fp + idx);
    float4 b = *(const float4*)(fp + idx + 4);
    f16x8 t;
    t[0] = (_Float16)a.x; t[1] = (_Float16)a.y; t[2] = (_Float16)a.z; t[3] = (_Float16)a.w;
    t[4] = (_Float16)b.x; t[5] = (_Float16)b.y; t[6] = (_Float16)b.z; t[7] = (_Float16)b.w;
    return t;
  }
}

// LDS layout (bytes), total 156544 (<160 KiB, 1 WG/CU) — identical to v8 (verified):
//   q_base : 0      .. 65536   Q [32 q][1024 d] f16, byte=(q*2048+d*2)^((q&7)<<4)
//   s_lds  : 65536  .. 82432   S f32 [32 q][132]
//   p_base : 82432  .. 90624   P [32 q][128 s] f16, byte=(q*256+s*2)^((q&7)<<4)
//   vt     : 90624  .. 156160  8 x 8192 per-wave V-transpose [128 h][32 s]
//   m/l/c  : 156160 .. 156544  softmax state
template<bool WS16>
__global__ __launch_bounds__(NT_, 2)
void attn_v9(const float* __restrict__ hid,
             const float* __restrict__ enc,
             const _Float16* __restrict__ encH,
             float* __restrict__ out) {
  __shared__ __attribute__((aligned(16))) char smem[156544];
  char*  const q_base = smem;
  float* const s_lds  = (float*)(smem + 65536);
  char*  const p_base = smem + 82432;
  char*  const vt_all = smem + 90624;
  float* const m_lds  = (float*)(smem + 156160);
  float* const l_lds  = m_lds + 32;
  float* const c_lds  = m_lds + 64;

  const int tid  = threadIdx.x;
  const int lane = tid & 63;
  const int wid  = tid >> 6;
  const int arow = lane & 15;
  const int agrp = lane >> 4;

  // XCD-affine: XCD x sweeps all 64 q-tiles of batch x, then batch x+8.
  const int bi  = blockIdx.x;
  const int x   = bi & 7;
  const int idx = bi >> 3;
  const int b   = x + 8 * (idx >> 6);
  const int q0  = (idx & 63) * QB_;

  const int hw = wid;  // PV h-chunk (128 wide); QK^T s-chunk = wid*16

  if (tid < 32) { m_lds[tid] = -__builtin_inff(); l_lds[tid] = 0.0f; }

  // ---- stage Q (32 x 1024) fp32 -> f16 into LDS, swizzled ----
  {
    const float* qsrc = hid + ((size_t)b * TQ_ + q0) * DH_;
    #pragma unroll
    for (int k = 0; k < 16; ++k) {
      int i = tid + k * NT_;
      int q = i >> 8;
      int h = (i & 255) * 4;
      float4 v = *(const float4*)(qsrc + (size_t)q * DH_ + h);
      int byte = (q * 2048 + h * 2) ^ ((q & 7) << 4);
      *(uint32_t*)(q_base + byte)     = pack_h2(v.x, v.y);
      *(uint32_t*)(q_base + byte + 4) = pack_h2(v.z, v.w);
    }
  }
  __syncthreads();

  f32x4 o_acc[2][8];   // 64 AGPR persistent
  #pragma unroll
  for (int m = 0; m < 2; ++m)
    #pragma unroll
    for (int n = 0; n < 8; ++n)
      o_acc[m][n] = {};

  char* const vt = vt_all + wid * 8192;
  const size_t enc_b = (size_t)b * TS_ * DH_;
  const int h8  = (lane & 15) * 8;
  const int spb = (lane >> 4) * 2;

  for (int st = 0; st < TS_ / SB_; ++st) {
    const int s0 = st * SB_;

    // ---- issue PV phase-0 V loads FIRST (hide under all of QK^T + softmax) ----
    f16x8 stg[4][2];
    #pragma unroll
    for (int it = 0; it < 4; ++it) {
      size_t base = enc_b + (size_t)(s0 + it * 8 + spb) * DH_ + hw * 128 + h8;
      stg[it][0] = ld8<WS16>(encH, enc, base);
      stg[it][1] = ld8<WS16>(encH, enc, base + DH_);
    }

    // ================= QK^T: full-d S[32q][16s], 4 accumulator chains =================
    f32x4 sacc0a = {}, sacc0b = {}, sacc1a = {}, sacc1b = {};
    {
      const size_t krow = enc_b + (size_t)(s0 + wid * 16 + arow) * DH_;
      #pragma unroll
      for (int kp = 0; kp < 16; ++kp) {
        // even chain
        {
          const int d = (2 * kp) * 32 + agrp * 8;
          f16x8 bf  = ld8<WS16>(encH, enc, krow + d);
          f16x8 af0 = *(const f16x8*)(q_base + ((arow * 2048 + d * 2) ^ ((arow & 7) << 4)));
          f16x8 af1 = *(const f16x8*)(q_base + (((16 + arow) * 2048 + d * 2) ^ ((arow & 7) << 4)));
          sacc0a = __builtin_amdgcn_mfma_f32_16x16x32_f16(af0, bf, sacc0a, 0, 0, 0);
          sacc1a = __builtin_amdgcn_mfma_f32_16x16x32_f16(af1, bf, sacc1a, 0, 0, 0);
        }
        // odd chain
        {
          const int d = (2 * kp + 1) * 32 + agrp * 8;
          f16x8 bf  = ld8<WS16>(encH, enc, krow + d);
          f16x8 af0 = *(const f16x8*)(q_base + ((arow * 2048 + d * 2) ^ ((arow & 7) << 4)));
          f16x8 af1 = *(const f16x8*)(q_base + (((16 + arow) * 2048 + d * 2) ^ ((arow & 7) << 4)));
          sacc0b = __builtin_amdgcn_mfma_f32_16x16x32_f16(af0, bf, sacc0b, 0, 0, 0);
          sacc1b = __builtin_amdgcn_mfma_f32_16x16x32_f16(af1, bf, sacc1b, 0, 0, 0);
        }
      }
    }

    // write S tile (single writer per element): row=q, col = wid*16 + arow
    {
      const int sc = wid * 16 + arow;
      f32x4 s0v = sacc0a + sacc0b;
      f32x4 s1v = sacc1a + sacc1b;
      #pragma unroll
      for (int i2 = 0; i2 < 4; ++i2) {
        s_lds[(agrp * 4 + i2) * 132 + sc]      = s0v[i2];
        s_lds[(16 + agrp * 4 + i2) * 132 + sc] = s1v[i2];
      }
    }

    LDS_BARRIER();  // b1: S complete (V loads stay in flight)

    // ================= online softmax over [32 q][128 s] =================
    {
      int q = tid >> 4, sq = tid & 15;
      const float* bp = s_lds + q * 132 + sq * 4;
      f32x4 va = *(const f32x4*)bp;
      f32x4 vb = *(const f32x4*)(bp + 64);
      float mx = fmaxf(fmaxf(fmaxf(va[0], va[1]), fmaxf(va[2], va[3])),
                       fmaxf(fmaxf(vb[0], vb[1]), fmaxf(vb[2], vb[3])));
      #pragma unroll
      for (int o = 8; o; o >>= 1) mx = fmaxf(mx, __shfl_xor(mx, o));
      float mprev = m_lds[q];
      float mnew  = fmaxf(mprev, mx);
      float pa0 = __expf(va[0] - mnew), pa1 = __expf(va[1] - mnew);
      float pa2 = __expf(va[2] - mnew), pa3 = __expf(va[3] - mnew);
      float pb0 = __expf(vb[0] - mnew), pb1 = __expf(vb[1] - mnew);
      float pb2 = __expf(vb[2] - mnew), pb3 = __expf(vb[3] - mnew);
      float ps = ((pa0 + pa1) + (pa2 + pa3)) + ((pb0 + pb1) + (pb2 + pb3));
      #pragma unroll
      for (int o = 8; o; o >>= 1) ps += __shfl_xor(ps, o);
      if (sq == 0) {
        float cf = __expf(mprev - mnew);
        m_lds[q] = mnew;
        l_lds[q] = l_lds[q] * cf + ps;
        c_lds[q] = cf;
      }
      f16x4 pwa, pwb;
      pwa[0] = (_Float16)pa0; pwa[1] = (_Float16)pa1;
      pwa[2] = (_Float16)pa2; pwa[3] = (_Float16)pa3;
      pwb[0] = (_Float16)pb0; pwb[1] = (_Float16)pb1;
      pwb[2] = (_Float16)pb2; pwb[3] = (_Float16)pb3;
      *(f16x4*)(p_base + ((q * 256 + sq * 8) ^ ((q & 7) << 4)))       = pwa;
      *(f16x4*)(p_base + ((q * 256 + 128 + sq * 8) ^ ((q & 7) << 4))) = pwb;
    }

    LDS_BARRIER();  // b2: P + m/l/c complete

    // ---- rescale O ----
    #pragma unroll
    for (int m = 0; m < 2; ++m)
      #pragma unroll
      for (int i2 = 0; i2 < 4; ++i2) {
        float cf = c_lds[m * 16 + agrp * 4 + i2];
        #pragma unroll
        for (int n = 0; n < 8; ++n) o_acc[m][n][i2] *= cf;
      }

    // ================= PV: 4 phases of 32 s =================
    #pragma unroll
    for (int ph = 0; ph < 4; ++ph) {
      // write Vt (wave-private, DS in-order, no barrier)
      #pragma unroll
      for (int it = 0; it < 4; ++it) {
        int sp = it * 8 + spb;
        #pragma unroll
        for (int jj = 0; jj < 8; ++jj) {
          int hloc = h8 + jj;
          union { _Float16 h[2]; uint32_t u; } pk;
          pk.h[0] = stg[it][0][jj]; pk.h[1] = stg[it][1][jj];
          *(uint32_t*)(vt + ((hloc * 64 + sp * 2) ^ (((hloc >> 3) & 7) << 4))) = pk.u;
        }
      }
      // issue next phase's V loads (overlap with MFMAs below)
      if (ph < 3) {
        #pragma unroll
        for (int it = 0; it < 4; ++it) {
          size_t base = enc_b + (size_t)(s0 + (ph + 1) * 32 + it * 8 + spb) * DH_ + hw * 128 + h8;
          stg[it][0] = ld8<WS16>(encH, enc, base);
          stg[it][1] = ld8<WS16>(encH, enc, base + DH_);
        }
      }
      // P A-frags for this phase
      f16x8 paf0 = *(const f16x8*)(p_base +
          ((arow * 256 + ph * 64 + agrp * 16) ^ ((arow & 7) << 4)));
      f16x8 paf1 = *(const f16x8*)(p_base +
          (((16 + arow) * 256 + ph * 64 + agrp * 16) ^ ((arow & 7) << 4)));
      __builtin_amdgcn_s_setprio(1);
      #pragma unroll
      for (int n = 0; n < 8; ++n) {
        int hloc = n * 16 + arow;
        f16x8 bv = *(const f16x8*)(vt + ((hloc * 64 + agrp * 16) ^ (((hloc >> 3) & 7) << 4)));
        o_acc[0][n] = __builtin_amdgcn_mfma_f32_16x16x32_f16(paf0, bv, o_acc[0][n], 0, 0, 0);
        o_acc[1][n] = __builtin_amdgcn_mfma_f32_16x16x32_f16(paf1, bv, o_acc[1][n], 0, 0, 0);
      }
      __builtin_amdgcn_s_setprio(0);
    }
  }

  // ================= epilogue: O / l =================
  #pragma unroll
  for (int m = 0; m < 2; ++m) {
    #pragma unroll
    for (int i2 = 0; i2 < 4; ++i2) {
      int qr = m * 16 + agrp * 4 + i2;
      float inv = 1.0f / l_lds[qr];
      #pragma unroll
      for (int n = 0; n < 8; ++n) {
        out[((size_t)(b * TQ_ + q0 + qr)) * DH_ + hw * 128 + n * 16 + arow] =
            o_acc[m][n][i2] * inv;
      }
    }
  }
}

extern "C" void kernel_launch(void* const* d_in, const int* in_sizes, int n_in,
                              void* d_out, int out_size, void* d_ws, size_t ws_size,
                              hipStream_t stream) {
  (void)in_sizes; (void)n_in; (void)out_size;
  const float* hid = (const float*)d_in[0];
  const float* enc = (const float*)d_in[1];
  float* out = (float*)d_out;

  const size_t encN = (size_t)NB_ * TS_ * DH_;
  const bool ws16 = (ws_size >= encN * sizeof(_Float16));

  dim3 grid(NB_ * (TQ_ / QB_), 1, 1);
  dim3 block(NT_, 1, 1);

  if (ws16) {
    _Float16* encH = (_Float16*)d_ws;
    convert_f32_f16<<<dim3((unsigned)(encN / 8 / 256)), dim3(256), 0, stream>>>(enc, encH);
    attn_v9<true><<<grid, block, 0, stream>>>(hid, enc, encH, out);
  } else {
    attn_v9<false><<<grid, block, 0, stream>>>(hid, enc, nullptr, out);
  }
}

// Round 10
// 866.693 us; speedup vs baseline: 1.0400x; 1.0400x over previous
//
#include <hip/hip_runtime.h>

#define NB_ 16
#define TQ_ 2048
#define TS_ 2048
#define DH_ 1024
#define QB_ 32
#define SB_ 128
#define NT_ 512

typedef _Float16 f16x8 __attribute__((ext_vector_type(8)));
typedef _Float16 f16x4 __attribute__((ext_vector_type(4)));
typedef float f32x4 __attribute__((ext_vector_type(4)));

// LDS-domain barrier: does NOT drain vmcnt; in-flight global loads survive.
#define LDS_BARRIER() asm volatile("s_waitcnt lgkmcnt(0)\n\ts_barrier" ::: "memory")

__global__ void convert_f32_f16(const float* __restrict__ src, _Float16* __restrict__ dst) {
  size_t i = ((size_t)blockIdx.x * blockDim.x + threadIdx.x) * 8;
  float4 v0 = *(const float4*)(src + i);
  float4 v1 = *(const float4*)(src + i + 4);
  f16x8 o;
  o[0] = (_Float16)v0.x; o[1] = (_Float16)v0.y; o[2] = (_Float16)v0.z; o[3] = (_Float16)v0.w;
  o[4] = (_Float16)v1.x; o[5] = (_Float16)v1.y; o[6] = (_Float16)v1.z; o[7] = (_Float16)v1.w;
  *(f16x8*)(dst + i) = o;
}

__device__ inline f16x8 cvt8(const float* __restrict__ fp) {
  float4 a = *(const float4*)fp;
  float4 b = *(const float4*)(fp + 4);
  f16x8 t;
  t[0] = (_Float16)a.x; t[1] = (_Float16)a.y; t[2] = (_Float16)a.z; t[3] = (_Float16)a.w;
  t[4] = (_Float16)b.x; t[5] = (_Float16)b.y; t[6] = (_Float16)b.z; t[7] = (_Float16)b.w;
  return t;
}

template<bool WS16>
__device__ inline f16x8 ld8(const _Float16* __restrict__ hp, const float* __restrict__ fp, size_t idx) {
  if constexpr (WS16) return *(const f16x8*)(hp + idx);
  else return cvt8(fp + idx);
}

// LDS layout (bytes), total 143744 (1 WG/CU):
//   vt     : 0      .. 65536   8 x 8192 per-wave V-transpose [128 h][32 s]   [v2-verified]
//            byte = (h*64 + s*2) ^ (((h>>3)&7)<<4)
//   s_tiles: 65536  .. 135168  8 tiles [(sh*4+dw)][32 q][68] f32 (partial S over d-chunk)
//   p_base : 135168 .. 143360  P [32 q][128 s] f16, byte=(q*256+s*2)^((q&7)<<4)  [v8-verified]
//   m/l/c  : 143360 .. 143744  softmax state
template<bool WS16>
__global__ __launch_bounds__(NT_, 2)
void attn_v10(const float* __restrict__ hid,
              const float* __restrict__ enc,
              const _Float16* __restrict__ encH,
              float* __restrict__ out) {
  __shared__ __attribute__((aligned(16))) char smem[143744];
  char*  const vt_all  = smem;
  float* const s_tiles = (float*)(smem + 65536);
  char*  const p_base  = smem + 135168;
  float* const m_lds   = (float*)(smem + 143360);
  float* const l_lds   = m_lds + 32;
  float* const c_lds   = m_lds + 64;

  const int tid  = threadIdx.x;
  const int lane = tid & 63;
  const int wid  = tid >> 6;
  const int arow = lane & 15;
  const int agrp = lane >> 4;

  // XCD-affine: XCD x sweeps all 64 q-tiles of batch x, then batch x+8.
  const int bi  = blockIdx.x;
  const int x   = bi & 7;
  const int idx = bi >> 3;
  const int b   = x + 8 * (idx >> 6);
  const int q0  = (idx & 63) * QB_;

  const int dw = wid & 3;   // QK^T d-chunk (256 wide)
  const int sh = wid >> 2;  // QK^T s-half (64 wide)
  const int hw = wid;       // PV h-chunk (128 wide)

  if (tid < 32) { m_lds[tid] = -__builtin_inff(); l_lds[tid] = 0.0f; }

  // ---- Q fragments in registers (persistent, 64 VGPR; v2-verified no-spill) ----
  f16x8 a_q[2][8];
  #pragma unroll
  for (int m = 0; m < 2; ++m) {
    #pragma unroll
    for (int kf = 0; kf < 8; ++kf) {
      const float* qp = hid + ((size_t)(b * TQ_ + q0 + m * 16 + arow)) * DH_
                            + dw * 256 + kf * 32 + agrp * 8;
      a_q[m][kf] = cvt8(qp);
    }
  }

  f32x4 o_acc[2][8];   // 64 AGPR persistent
  #pragma unroll
  for (int m = 0; m < 2; ++m)
    #pragma unroll
    for (int n = 0; n < 8; ++n)
      o_acc[m][n] = {};

  char* const vt = vt_all + wid * 8192;
  const size_t enc_b = (size_t)b * TS_ * DH_;
  const int h8  = (lane & 15) * 8;   // V staging h-octet
  const int spb = (lane >> 4) * 2;   // V staging s-pair base

  for (int st = 0; st < TS_ / SB_; ++st) {
    const int s0 = st * SB_;

    // ================= QK^T: partial S[32q][64s] over d-chunk dw =================
    f32x4 sacc[2][4] = {{{}, {}, {}, {}}, {{}, {}, {}, {}}};
    #pragma unroll
    for (int kf = 0; kf < 8; ++kf) {
      const int d = dw * 256 + kf * 32 + agrp * 8;
      f16x8 bf[4];
      #pragma unroll
      for (int n = 0; n < 4; ++n) {
        size_t kb = enc_b + (size_t)(s0 + sh * 64 + n * 16 + arow) * DH_ + d;
        bf[n] = ld8<WS16>(encH, enc, kb);
      }
      #pragma unroll
      for (int n = 0; n < 4; ++n) {
        sacc[0][n] = __builtin_amdgcn_mfma_f32_16x16x32_f16(a_q[0][kf], bf[n], sacc[0][n], 0, 0, 0);
        sacc[1][n] = __builtin_amdgcn_mfma_f32_16x16x32_f16(a_q[1][kf], bf[n], sacc[1][n], 0, 0, 0);
      }
    }

    // ---- issue PV phase-0 V loads (v8 position: in flight across both barriers) ----
    f16x8 stg[4][2];
    #pragma unroll
    for (int it = 0; it < 4; ++it) {
      size_t base = enc_b + (size_t)(s0 + it * 8 + spb) * DH_ + hw * 128 + h8;
      stg[it][0] = ld8<WS16>(encH, enc, base);
      stg[it][1] = ld8<WS16>(encH, enc, base + DH_);
    }

    // write partial S tile (sh*4+dw): [32 q][68] f32 (2-way bank aliasing = free)
    {
      float* tp = s_tiles + (size_t)(sh * 4 + dw) * (32 * 68);
      #pragma unroll
      for (int m = 0; m < 2; ++m)
        #pragma unroll
        for (int n = 0; n < 4; ++n)
          #pragma unroll
          for (int i2 = 0; i2 < 4; ++i2)
            tp[(m * 16 + agrp * 4 + i2) * 68 + n * 16 + arow] = sacc[m][n][i2];
    }

    LDS_BARRIER();  // b1: S complete (V loads stay in flight)

    // ================= online softmax over [32 q][128 s] =================
    {
      int q = tid >> 4, sq = tid & 15;
      const float* bp = s_tiles + q * 68 + sq * 4;
      f32x4 va = *(const f32x4*)bp;                    // sh=0 partials, dw=0..3
      va += *(const f32x4*)(bp + 2176);
      va += *(const f32x4*)(bp + 4352);
      va += *(const f32x4*)(bp + 6528);
      const float* bq = bp + 8704;                     // sh=1 partials
      f32x4 vb = *(const f32x4*)bq;
      vb += *(const f32x4*)(bq + 2176);
      vb += *(const f32x4*)(bq + 4352);
      vb += *(const f32x4*)(bq + 6528);
      float mx = fmaxf(fmaxf(fmaxf(va[0], va[1]), fmaxf(va[2], va[3])),
                       fmaxf(fmaxf(vb[0], vb[1]), fmaxf(vb[2], vb[3])));
      #pragma unroll
      for (int o = 8; o; o >>= 1) mx = fmaxf(mx, __shfl_xor(mx, o));
      float mprev = m_lds[q];
      float mnew  = fmaxf(mprev, mx);
      float pa0 = __expf(va[0] - mnew), pa1 = __expf(va[1] - mnew);
      float pa2 = __expf(va[2] - mnew), pa3 = __expf(va[3] - mnew);
      float pb0 = __expf(vb[0] - mnew), pb1 = __expf(vb[1] - mnew);
      float pb2 = __expf(vb[2] - mnew), pb3 = __expf(vb[3] - mnew);
      float ps = ((pa0 + pa1) + (pa2 + pa3)) + ((pb0 + pb1) + (pb2 + pb3));
      #pragma unroll
      for (int o = 8; o; o >>= 1) ps += __shfl_xor(ps, o);
      if (sq == 0) {
        float cf = __expf(mprev - mnew);
        m_lds[q] = mnew;
        l_lds[q] = l_lds[q] * cf + ps;
        c_lds[q] = cf;
      }
      f16x4 pwa, pwb;
      pwa[0] = (_Float16)pa0; pwa[1] = (_Float16)pa1;
      pwa[2] = (_Float16)pa2; pwa[3] = (_Float16)pa3;
      pwb[0] = (_Float16)pb0; pwb[1] = (_Float16)pb1;
      pwb[2] = (_Float16)pb2; pwb[3] = (_Float16)pb3;
      *(f16x4*)(p_base + ((q * 256 + sq * 8) ^ ((q & 7) << 4)))       = pwa;
      *(f16x4*)(p_base + ((q * 256 + 128 + sq * 8) ^ ((q & 7) << 4))) = pwb;
    }

    LDS_BARRIER();  // b2: P + m/l/c complete

    // ---- rescale O ----
    #pragma unroll
    for (int m = 0; m < 2; ++m)
      #pragma unroll
      for (int i2 = 0; i2 < 4; ++i2) {
        float cf = c_lds[m * 16 + agrp * 4 + i2];
        #pragma unroll
        for (int n = 0; n < 8; ++n) o_acc[m][n][i2] *= cf;
      }

    // ================= PV: 4 phases of 32 s (v2-verified vt structure) =================
    #pragma unroll
    for (int ph = 0; ph < 4; ++ph) {
      // write Vt (wave-private, DS in-order, no barrier)
      #pragma unroll
      for (int it = 0; it < 4; ++it) {
        int sp = it * 8 + spb;
        #pragma unroll
        for (int jj = 0; jj < 8; ++jj) {
          int hloc = h8 + jj;
          union { _Float16 h[2]; uint32_t u; } pk;
          pk.h[0] = stg[it][0][jj]; pk.h[1] = stg[it][1][jj];
          *(uint32_t*)(vt + ((hloc * 64 + sp * 2) ^ (((hloc >> 3) & 7) << 4))) = pk.u;
        }
      }
      // issue next phase's V loads (overlap with MFMAs below)
      if (ph < 3) {
        #pragma unroll
        for (int it = 0; it < 4; ++it) {
          size_t base = enc_b + (size_t)(s0 + (ph + 1) * 32 + it * 8 + spb) * DH_ + hw * 128 + h8;
          stg[it][0] = ld8<WS16>(encH, enc, base);
          stg[it][1] = ld8<WS16>(encH, enc, base + DH_);
        }
      }
      // P A-frags for this phase
      f16x8 paf0 = *(const f16x8*)(p_base +
          ((arow * 256 + ph * 64 + agrp * 16) ^ ((arow & 7) << 4)));
      f16x8 paf1 = *(const f16x8*)(p_base +
          (((16 + arow) * 256 + ph * 64 + agrp * 16) ^ ((arow & 7) << 4)));
      __builtin_amdgcn_s_setprio(1);
      #pragma unroll
      for (int n = 0; n < 8; ++n) {
        int hloc = n * 16 + arow;
        f16x8 bv = *(const f16x8*)(vt + ((hloc * 64 + agrp * 16) ^ (((hloc >> 3) & 7) << 4)));
        o_acc[0][n] = __builtin_amdgcn_mfma_f32_16x16x32_f16(paf0, bv, o_acc[0][n], 0, 0, 0);
        o_acc[1][n] = __builtin_amdgcn_mfma_f32_16x16x32_f16(paf1, bv, o_acc[1][n], 0, 0, 0);
      }
      __builtin_amdgcn_s_setprio(0);
    }
  }

  // ================= epilogue: O / l =================
  #pragma unroll
  for (int m = 0; m < 2; ++m) {
    #pragma unroll
    for (int i2 = 0; i2 < 4; ++i2) {
      int qr = m * 16 + agrp * 4 + i2;
      float inv = 1.0f / l_lds[qr];
      #pragma unroll
      for (int n = 0; n < 8; ++n) {
        out[((size_t)(b * TQ_ + q0 + qr)) * DH_ + hw * 128 + n * 16 + arow] =
            o_acc[m][n][i2] * inv;
      }
    }
  }
}

extern "C" void kernel_launch(void* const* d_in, const int* in_sizes, int n_in,
                              void* d_out, int out_size, void* d_ws, size_t ws_size,
                              hipStream_t stream) {
  (void)in_sizes; (void)n_in; (void)out_size;
  const float* hid = (const float*)d_in[0];
  const float* enc = (const float*)d_in[1];
  float* out = (float*)d_out;

  const size_t encN = (size_t)NB_ * TS_ * DH_;
  const bool ws16 = (ws_size >= encN * sizeof(_Float16));

  dim3 grid(NB_ * (TQ_ / QB_), 1, 1);
  dim3 block(NT_, 1, 1);

  if (ws16) {
    _Float16* encH = (_Float16*)d_ws;
    convert_f32_f16<<<dim3((unsigned)(encN / 8 / 256)), dim3(256), 0, stream>>>(enc, encH);
    attn_v10<true><<<grid, block, 0, stream>>>(hid, enc, encH, out);
  } else {
    attn_v10<false><<<grid, block, 0, stream>>>(hid, enc, nullptr, out);
  }
}